// Round 12
// baseline (170.206 us; speedup 1.0000x reference)
//
#include <hip/hip_runtime.h>
#include <math.h>

#define NR 4096
#define HD 512
#define NJR 32
#define INV_T 10.0f

typedef __attribute__((ext_vector_type(8))) short bf16x8;
typedef __attribute__((ext_vector_type(4))) short short4v;
typedef __attribute__((ext_vector_type(4))) float f32x4;

typedef const unsigned int __attribute__((address_space(1)))* gas_t;
typedef unsigned int __attribute__((address_space(3)))* las_t;

__device__ __forceinline__ unsigned short f2bf(float f) {
  union { float f; unsigned u; } v; v.f = f;
  unsigned r = v.u + 0x7fff + ((v.u >> 16) & 1);
  return (unsigned short)(r >> 16);
}
__device__ __forceinline__ float bf2f(unsigned short b) {
  union { unsigned u; float f; } v; v.u = ((unsigned)b) << 16;
  return v.f;
}

// ======== fragment-major layout ========
// matrix [M][K]: fragment (rf=r>>4, ks=c>>5) = 1024B slot at (rf*(K>>5)+ks)*1024.
// lane l holds bf16x8 at lane*16: row = rf*16+(l&15), cols ks*32+(l>>4)*4+{0..3,16..19}.

// ---------------------------------------------------------------- prep (R10 + rep loop)
__global__ __launch_bounds__(256) void prep(
    const float* __restrict__ s, const float* __restrict__ sp,
    const float* __restrict__ a1h,
    unsigned short* __restrict__ Sb, unsigned short* __restrict__ SPb,
    int* __restrict__ aidx, float* __restrict__ sqp,
    const float* __restrict__ pW0, unsigned short* __restrict__ pW0t,
    const float* __restrict__ pW1, unsigned short* __restrict__ pW1t,
    const float* __restrict__ pW2, unsigned short* __restrict__ pW2t,
    const float* __restrict__ gW0, unsigned short* __restrict__ gW0t,
    const float* __restrict__ gW1, unsigned short* __restrict__ gW1t,
    const float* __restrict__ gW2, unsigned short* __restrict__ gW2t,
    float* __restrict__ out, int reps) {
  int b = blockIdx.x, tid = threadIdx.x;
  for (int rep = 0; rep < reps; ++rep) {
    if (b < 16) {
      int r = b * 256 + tid;
      int a = 0;
#pragma unroll
      for (int j = 0; j < 4; ++j) if (a1h[(size_t)r * 4 + j] > 0.5f) a = j;
      aidx[r] = a;
      sqp[r] = 0.f;
      if (b == 0 && tid == 0) out[0] = 0.f;
      continue;
    }
    const int idx8 = tid & 127;
    const int h = idx8 & 1, p = idx8 >> 1, hi = p >> 4, l15 = p & 15;
    if (b < 2064) {
      const float* src = (b < 1040) ? s : sp;
      unsigned short* dst = (b < 1040) ? Sb : SPb;
      int lb = (b < 1040) ? b - 16 : b - 1040;
      int s0 = lb * 2 + (tid >> 7);
      int rf = s0 >> 3, ks = s0 & 7;
      int row = rf * 16 + l15, c0 = ks * 32 + hi * 4 + h * 16;
      float4 v = *(const float4*)&src[(size_t)row * 256 + c0];
      short4v o = { (short)f2bf(v.x), (short)f2bf(v.y), (short)f2bf(v.z), (short)f2bf(v.w) };
      *(short4v*)((char*)dst + (size_t)s0 * 1024 + idx8 * 8) = o;
      continue;
    }
    int local = b - 2064;
    const float* W; unsigned short* Wt; int N, ksh;
    if (local < 128)      { W = pW0; Wt = pW0t; N = 512; ksh = 3; }
    else if (local < 384) { W = pW1; Wt = pW1t; N = 512; ksh = 4; local -= 128; }
    else if (local < 448) { W = pW2; Wt = pW2t; N = 128; ksh = 4; local -= 384; }
    else if (local < 576) { W = gW0; Wt = gW0t; N = 512; ksh = 3; local -= 448; }
    else if (local < 832) { W = gW1; Wt = gW1t; N = 512; ksh = 4; local -= 576; }
    else                  { W = gW2; Wt = gW2t; N = 128; ksh = 4; local -= 832; }
    int s0 = local * 2 + (tid >> 7);
    int rf = s0 >> ksh, ks = s0 & ((1 << ksh) - 1);
    int n = rf * 16 + l15, k0 = ks * 32 + hi * 4 + h * 16;
    short4v o = { (short)f2bf(W[(size_t)(k0 + 0) * N + n]),
                  (short)f2bf(W[(size_t)(k0 + 1) * N + n]),
                  (short)f2bf(W[(size_t)(k0 + 2) * N + n]),
                  (short)f2bf(W[(size_t)(k0 + 3) * N + n]) };
    *(short4v*)((char*)Wt + (size_t)s0 * 1024 + idx8 * 8) = o;
  }
}

// ---------------------------------------------------------------- small-tile dbuf GEMM (R10 + rep loop)
template <int BM, int BN, int K, bool RELU, bool GB, bool SQ>
__global__ __launch_bounds__(256) void gemm_db(
    const unsigned short* __restrict__ A0, const unsigned short* __restrict__ A1,
    const unsigned short* __restrict__ W0, const unsigned short* __restrict__ W1,
    const float* __restrict__ b0, const float* __restrict__ b1,
    unsigned short* __restrict__ C0, unsigned short* __restrict__ C1,
    float* __restrict__ sqp, int N,
    const int* __restrict__ aidx, const float* __restrict__ gW0f, int reps) {
  constexpr int KS = K >> 5;
  constexpr int NSTEP = K >> 6;
  constexpr int ABY = BM * 128;
  constexpr int BBY = BN * 128;
  constexpr int RFW = BM >> 5;
  constexpr int FNW = BN >> 5;
  constexpr int V = RFW + FNW;
  __shared__ char lds[2 * (ABY + BBY)];
  char* As = lds;
  char* Bs = lds + 2 * ABY;

  const int tid = threadIdx.x, lane = tid & 63, w = tid >> 6;
  const int wm = w >> 1, wn = w & 1;
  const int z = blockIdx.z;
  const char* Ab = (const char*)(z ? A1 : A0);
  const char* Wb = (const char*)(z ? W1 : W0);
  const float* bias = z ? b1 : b0;
  char* Cb = (char*)(z ? C1 : C0);
  const int bm = blockIdx.x * BM, bn = blockIdx.y * BN;
  const int lane16 = lane * 16;

  auto stage = [&](int buf, int st) {
#pragma unroll
    for (int u = 0; u < RFW; ++u) {
      const int sl = w * RFW + u;
      const char* src = Ab + ((size_t)((bm >> 4) + (sl >> 1)) * KS + st * 2 + (sl & 1)) * 1024 + lane16;
      __builtin_amdgcn_global_load_lds((gas_t)src, (las_t)(As + buf * ABY + sl * 1024), 16, 0, 0);
    }
#pragma unroll
    for (int u = 0; u < FNW; ++u) {
      const int sl = w * FNW + u;
      const char* src = Wb + ((size_t)((bn >> 4) + (sl >> 1)) * KS + st * 2 + (sl & 1)) * 1024 + lane16;
      __builtin_amdgcn_global_load_lds((gas_t)src, (las_t)(Bs + buf * BBY + sl * 1024), 16, 0, 0);
    }
  };

  for (int rep = 0; rep < reps; ++rep) {
    f32x4 acc[RFW][FNW] = {};
    stage(0, 0);
#pragma unroll
    for (int st = 0; st < NSTEP; ++st) {
      const int buf = st & 1;
      if (st + 1 < NSTEP) {
        stage(buf ^ 1, st + 1);
        if constexpr (V == 4) asm volatile("s_waitcnt vmcnt(4)" ::: "memory");
        else                  asm volatile("s_waitcnt vmcnt(3)" ::: "memory");
      } else {
        asm volatile("s_waitcnt vmcnt(0)" ::: "memory");
      }
      __builtin_amdgcn_s_barrier();
#pragma unroll
      for (int kss = 0; kss < 2; ++kss) {
        bf16x8 af[RFW], bfv[FNW];
#pragma unroll
        for (int i = 0; i < RFW; ++i)
          af[i] = *(const bf16x8*)(As + buf * ABY + ((wm * RFW + i) * 2 + kss) * 1024 + lane16);
#pragma unroll
        for (int j = 0; j < FNW; ++j)
          bfv[j] = *(const bf16x8*)(Bs + buf * BBY + ((wn * FNW + j) * 2 + kss) * 1024 + lane16);
#pragma unroll
        for (int i = 0; i < RFW; ++i)
#pragma unroll
          for (int j = 0; j < FNW; ++j)
            acc[i][j] = __builtin_amdgcn_mfma_f32_16x16x32_bf16(bfv[j], af[i], acc[i][j], 0, 0, 0);
      }
      __builtin_amdgcn_s_barrier();
    }

    const int l15 = lane & 15, hi = lane >> 4;
    const int NS = N >> 5;
    const int row0 = bm + wm * (RFW * 16);
    const int col0 = bn + wn * (FNW * 16);
    int ar[RFW];
#pragma unroll
    for (int i = 0; i < RFW; ++i) ar[i] = 0;
    if (GB && z == 1) {
#pragma unroll
      for (int i = 0; i < RFW; ++i) ar[i] = aidx[row0 + i * 16 + l15];
    }
    if constexpr (FNW == 2) {
      float4 bi0 = *(const float4*)&bias[col0 + hi * 4];
      float4 bi1 = *(const float4*)&bias[col0 + 16 + hi * 4];
#pragma unroll
      for (int i = 0; i < RFW; ++i) {
        const int rfC = (row0 >> 4) + i;
        float v[8] = { acc[i][0][0] + bi0.x, acc[i][0][1] + bi0.y,
                       acc[i][0][2] + bi0.z, acc[i][0][3] + bi0.w,
                       acc[i][1][0] + bi1.x, acc[i][1][1] + bi1.y,
                       acc[i][1][2] + bi1.z, acc[i][1][3] + bi1.w };
        if (GB && z == 1) {
          float4 g0 = *(const float4*)&gW0f[(size_t)(256 + ar[i]) * N + col0 + hi * 4];
          float4 g1 = *(const float4*)&gW0f[(size_t)(256 + ar[i]) * N + col0 + 16 + hi * 4];
          v[0] += g0.x; v[1] += g0.y; v[2] += g0.z; v[3] += g0.w;
          v[4] += g1.x; v[5] += g1.y; v[6] += g1.z; v[7] += g1.w;
        }
        bf16x8 r;
#pragma unroll
        for (int t = 0; t < 8; ++t) {
          float vv = RELU ? fmaxf(v[t], 0.f) : v[t];
          r[t] = (short)f2bf(vv);
        }
        *(bf16x8*)(Cb + (size_t)(rfC * NS + (col0 >> 5)) * 1024 + lane16) = r;
      }
    } else {
      float4 bi0 = *(const float4*)&bias[col0 + hi * 4];
      float sq[RFW];
#pragma unroll
      for (int i = 0; i < RFW; ++i) sq[i] = 0.f;
#pragma unroll
      for (int i = 0; i < RFW; ++i) {
        const int rfC = (row0 >> 4) + i;
        float v[4] = { acc[i][0][0] + bi0.x, acc[i][0][1] + bi0.y,
                       acc[i][0][2] + bi0.z, acc[i][0][3] + bi0.w };
        short4v r;
#pragma unroll
        for (int t = 0; t < 4; ++t) {
          float vv = RELU ? fmaxf(v[t], 0.f) : v[t];
          unsigned short cv = f2bf(vv);
          r[t] = (short)cv;
          if (SQ) { float vb = bf2f(cv); sq[i] += vb * vb; }
        }
        *(short4v*)(Cb + (size_t)(rfC * NS + (bn >> 5)) * 1024 + lane16 + wn * 8) = r;
      }
      if (SQ && z == 1) {
#pragma unroll
        for (int i = 0; i < RFW; ++i) {
          float t = sq[i];
          t += __shfl_xor(t, 16, 64);
          t += __shfl_xor(t, 32, 64);
          if (lane < 16) atomicAdd(&sqp[row0 + i * 16 + lane], t);
        }
      }
    }
  }
}

// ---------------------------------------------------------------- logits (R10 + rep loop)
__global__ __launch_bounds__(256) void logits_fm(
    const unsigned short* __restrict__ Zb, const unsigned short* __restrict__ Zpb,
    const float* __restrict__ sqp, float* __restrict__ wm_,
    float* __restrict__ wsum, float* __restrict__ wdiag, int reps) {
  const int tid = threadIdx.x, lane = tid & 63, w = tid >> 6;
  const int l15 = lane & 15, hi = lane >> 4;
  const int i0 = blockIdx.x * 128, jr = blockIdx.y;
  const int row32 = i0 + w * 32;
  const int jbase = jr * 128;
  const int lane16 = lane * 16;
  const char* Zc = (const char*)Zb;
  const char* Pc = (const char*)Zpb;

  for (int rep = 0; rep < reps; ++rep) {
    bf16x8 afr[2][4];
#pragma unroll
    for (int rf = 0; rf < 2; ++rf)
#pragma unroll
      for (int ks = 0; ks < 4; ++ks)
        afr[rf][ks] = *(const bf16x8*)(Zc + (size_t)(((row32 >> 4) + rf) * 4 + ks) * 1024 + lane16);

    f32x4 acc[2][8] = {};
#pragma unroll
    for (int jf = 0; jf < 8; ++jf) {
      const size_t js = (size_t)((jbase >> 4) + jf) * 4;
#pragma unroll
      for (int ks = 0; ks < 4; ++ks) {
        bf16x8 bfv = *(const bf16x8*)(Pc + (js + ks) * 1024 + lane16);
        acc[0][jf] = __builtin_amdgcn_mfma_f32_16x16x32_bf16(bfv, afr[0][ks], acc[0][jf], 0, 0, 0);
        acc[1][jf] = __builtin_amdgcn_mfma_f32_16x16x32_bf16(bfv, afr[1][ks], acc[1][jf], 0, 0, 0);
      }
    }

#pragma unroll
    for (int rf = 0; rf < 2; ++rf) {
      const int grow = row32 + rf * 16 + l15;
      float mx = -INFINITY, dd = 0.f;
      bool hasd = false;
#pragma unroll
      for (int jf = 0; jf < 8; ++jf) {
        const int cb = jbase + jf * 16 + hi * 4;
        float4 q = *(const float4*)&sqp[cb];
        float sp[4] = { q.x, q.y, q.z, q.w };
#pragma unroll
        for (int e = 0; e < 4; ++e) {
          float lv = (2.f * acc[rf][jf][e] - sp[e]) * INV_T;
          acc[rf][jf][e] = lv;
          mx = fmaxf(mx, lv);
          if (cb + e == grow) { dd = lv; hasd = true; }
        }
      }
      mx = fmaxf(mx, __shfl_xor(mx, 16, 64));
      mx = fmaxf(mx, __shfl_xor(mx, 32, 64));
      float sum = 0.f;
#pragma unroll
      for (int jf = 0; jf < 8; ++jf)
#pragma unroll
        for (int e = 0; e < 4; ++e) sum += __expf(acc[rf][jf][e] - mx);
      sum += __shfl_xor(sum, 16, 64);
      sum += __shfl_xor(sum, 32, 64);
      if (hi == 0) {
        wm_[(size_t)jr * NR + grow] = mx;
        wsum[(size_t)jr * NR + grow] = sum;
      }
      if (hasd) wdiag[grow] = dd;
    }
  }
}

// ---------------------------------------------------------------- finalize (R10 verbatim)
__global__ __launch_bounds__(256) void finalize(const float* __restrict__ wm,
    const float* __restrict__ wsum, const float* __restrict__ wdiag,
    float* __restrict__ out) {
  int r = blockIdx.x * 256 + threadIdx.x;
  float mm = wm[r];
  float ss = wsum[r];
#pragma unroll
  for (int p = 1; p < NJR; ++p) {
    float mo = wm[(size_t)p * NR + r];
    float so = wsum[(size_t)p * NR + r];
    float mn = fmaxf(mm, mo);
    ss = ss * __expf(mm - mn) + so * __expf(mo - mn);
    mm = mn;
  }
  float loss_r = mm + logf(ss) - wdiag[r];
  float v = loss_r;
#pragma unroll
  for (int off = 32; off; off >>= 1) v += __shfl_xor(v, off, 64);
  __shared__ float partial[4];
  if ((threadIdx.x & 63) == 0) partial[threadIdx.x >> 6] = v;
  __syncthreads();
  if (threadIdx.x == 0)
    atomicAdd(out, (partial[0] + partial[1] + partial[2] + partial[3]) * (1.0f / (float)NR));
}

// ---------------------------------------------------------------- launch
// INSTRUMENTATION ROUND: prep/L0/L1/logits run with internal reps=8 so each
// dispatch (~40-100us) surfaces in rocprof top-5 with real counters.
// L2 (atomics) and finalize stay reps=1.
extern "C" void kernel_launch(void* const* d_in, const int* in_sizes, int n_in,
                              void* d_out, int out_size, void* d_ws, size_t ws_size,
                              hipStream_t stream) {
  const float* s   = (const float*)d_in[0];
  const float* sp  = (const float*)d_in[1];
  const float* a1h = (const float*)d_in[2];
  const float* pW0 = (const float*)d_in[3];
  const float* pb0 = (const float*)d_in[4];
  const float* pW1 = (const float*)d_in[5];
  const float* pb1 = (const float*)d_in[6];
  const float* pW2 = (const float*)d_in[7];
  const float* pb2 = (const float*)d_in[8];
  const float* gW0 = (const float*)d_in[9];
  const float* gb0 = (const float*)d_in[10];
  const float* gW1 = (const float*)d_in[11];
  const float* gb1 = (const float*)d_in[12];
  const float* gW2 = (const float*)d_in[13];
  const float* gb2 = (const float*)d_in[14];

  char* p = (char*)d_ws;
  unsigned short* Sb   = (unsigned short*)p; p += (size_t)NR * 256 * 2;
  unsigned short* SPb  = (unsigned short*)p; p += (size_t)NR * 256 * 2;
  unsigned short* H1   = (unsigned short*)p; p += (size_t)2 * NR * HD * 2;
  unsigned short* H2   = (unsigned short*)p; p += (size_t)2 * NR * HD * 2;
  unsigned short* Zall = (unsigned short*)p; p += (size_t)2 * NR * 128 * 2;
  unsigned short* pW0t = (unsigned short*)p; p += (size_t)256 * 512 * 2;
  unsigned short* pW1t = (unsigned short*)p; p += (size_t)512 * 512 * 2;
  unsigned short* pW2t = (unsigned short*)p; p += (size_t)512 * 128 * 2;
  unsigned short* gW0t = (unsigned short*)p; p += (size_t)256 * 512 * 2;
  unsigned short* gW1t = (unsigned short*)p; p += (size_t)512 * 512 * 2;
  unsigned short* gW2t = (unsigned short*)p; p += (size_t)512 * 128 * 2;
  float* sqp  = (float*)p; p += (size_t)NR * 4;
  float* wm   = (float*)p; p += (size_t)NJR * NR * 4;
  float* wsm  = (float*)p; p += (size_t)NJR * NR * 4;
  float* wdg  = (float*)p; p += (size_t)NR * 4;
  int*   aidx = (int*)p;  p += (size_t)NR * 4;

  unsigned short* H1g = H1 + (size_t)NR * HD;
  unsigned short* H2g = H2 + (size_t)NR * HD;
  unsigned short* Zb  = Zall;
  unsigned short* Zpb = Zall + (size_t)NR * 128;

  dim3 blk(256);
  prep<<<2960, blk, 0, stream>>>(s, sp, a1h, Sb, SPb, aidx, sqp,
                                 pW0, pW0t, pW1, pW1t, pW2, pW2t,
                                 gW0, gW0t, gW1, gW1t, gW2, gW2t,
                                 (float*)d_out, 8);

  gemm_db<64, 64, 256, true, true, false><<<dim3(64, 8, 2), blk, 0, stream>>>(
      Sb, SPb, pW0t, gW0t, pb0, gb0, H1, H1g, nullptr, 512, aidx, gW0, 8);
  gemm_db<64, 64, 512, true, false, false><<<dim3(64, 8, 2), blk, 0, stream>>>(
      H1, H1g, pW1t, gW1t, pb1, gb1, H2, H2g, nullptr, 512, nullptr, nullptr, 8);
  gemm_db<64, 32, 512, false, false, true><<<dim3(64, 4, 2), blk, 0, stream>>>(
      H2, H2g, pW2t, gW2t, pb2, gb2, Zb, Zpb, sqp, 128, nullptr, nullptr, 1);

  logits_fm<<<dim3(NR / 128, NJR), blk, 0, stream>>>(Zb, Zpb, sqp, wm, wsm, wdg, 8);
  finalize<<<NR / 256, blk, 0, stream>>>(wm, wsm, wdg, (float*)d_out);
}

// Round 13
// 69.247 us; speedup vs baseline: 2.4579x; 2.4579x over previous
//
#include <hip/hip_runtime.h>
#include <math.h>

#define NR 4096
#define HD 512
#define NJR 32
#define INV_T 10.0f
#define DONE_FINAL 1024   // done[line*16] lines<64; final counter at [1024]

typedef __attribute__((ext_vector_type(8))) short bf16x8;
typedef __attribute__((ext_vector_type(4))) short short4v;
typedef __attribute__((ext_vector_type(4))) float f32x4;

typedef const unsigned int __attribute__((address_space(1)))* gas_t;
typedef unsigned int __attribute__((address_space(3)))* las_t;

__device__ __forceinline__ unsigned short f2bf(float f) {
  union { float f; unsigned u; } v; v.f = f;
  unsigned r = v.u + 0x7fff + ((v.u >> 16) & 1);
  return (unsigned short)(r >> 16);
}
__device__ __forceinline__ float bf2f(unsigned short b) {
  union { unsigned u; float f; } v; v.u = ((unsigned)b) << 16;
  return v.f;
}

// ======== fragment-major layout ========
// matrix [M][K]: fragment (rf=r>>4, ks=c>>5) = 1024B slot at (rf*(K>>5)+ks)*1024.
// lane l holds bf16x8 at lane*16: row = rf*16+(l&15), cols ks*32+(l>>4)*4+{0..3,16..19}.

// ---------------------------------------------------------------- L0 fused:
// bid<1024: GEMM layer0 with in-kernel fp32 cast staging (A row-major fp32, W [K][N] fp32).
// bid>=1024: weight transpose-cast units for W1/W2 (consumed by later dispatches).
__global__ __launch_bounds__(256) void l0_fused(
    const float* __restrict__ s, const float* __restrict__ sp,
    const float* __restrict__ a1h,
    const float* __restrict__ pW0, const float* __restrict__ gW0,
    const float* __restrict__ pb0, const float* __restrict__ gb0,
    unsigned short* __restrict__ H1p, unsigned short* __restrict__ H1g,
    const float* __restrict__ pW1, unsigned short* __restrict__ pW1t,
    const float* __restrict__ pW2, unsigned short* __restrict__ pW2t,
    const float* __restrict__ gW1, unsigned short* __restrict__ gW1t,
    const float* __restrict__ gW2, unsigned short* __restrict__ gW2t) {
  const int bid = blockIdx.x, tid = threadIdx.x;
  if (bid >= 1024) {
    // ---- weight transpose-cast (K=512 for all) ----
    int local = bid - 1024;
    const float* W; unsigned short* Wt; int N;
    if (local < 256)      { W = pW1; Wt = pW1t; N = 512; }
    else if (local < 320) { W = pW2; Wt = pW2t; N = 128; local -= 256; }
    else if (local < 576) { W = gW1; Wt = gW1t; N = 512; local -= 320; }
    else                  { W = gW2; Wt = gW2t; N = 128; local -= 576; }
    const int idx8 = tid & 127;
    const int h = idx8 & 1, p = idx8 >> 1, hi = p >> 4, l15 = p & 15;
    int s0 = local * 2 + (tid >> 7);
    int rf = s0 >> 4, ks = s0 & 15;
    int n = rf * 16 + l15, k0 = ks * 32 + hi * 4 + h * 16;
    short4v o = { (short)f2bf(W[(size_t)(k0 + 0) * N + n]),
                  (short)f2bf(W[(size_t)(k0 + 1) * N + n]),
                  (short)f2bf(W[(size_t)(k0 + 2) * N + n]),
                  (short)f2bf(W[(size_t)(k0 + 3) * N + n]) };
    *(short4v*)((char*)Wt + (size_t)s0 * 1024 + idx8 * 8) = o;
    return;
  }
  // ---- GEMM: BM=64, BN=64, K=256 (4 steps of 64), cast staging, dbuf ----
  __shared__ __align__(1024) char As[2][8192];
  __shared__ __align__(1024) char Bs[2][8192];
  const int z = bid >> 9, rem = bid & 511;
  const int bx = rem & 63, by = rem >> 6;
  const float* A = z ? sp : s;
  const float* W = z ? gW0 : pW0;
  const float* bias = z ? gb0 : pb0;
  unsigned short* C = z ? H1g : H1p;
  const int lane = tid & 63, w = tid >> 6;
  const int wm = w >> 1, wn = w & 1;
  const int bm = bx * 64, bn = by * 64;
  const int lane16 = lane * 16;

  // A staging coords (2 entries/thread): e = q*256+tid
  int aslot[2], ale[2], arow[2], akb[2];
#pragma unroll
  for (int q = 0; q < 2; ++q) {
    int e = q * 256 + tid;
    aslot[q] = e >> 6; ale[q] = e & 63;
    arow[q] = bm + (aslot[q] >> 1) * 16 + (ale[q] & 15);
    akb[q] = (aslot[q] & 1) * 32 + (ale[q] >> 4) * 4;
  }
  // B staging coords (4 reads/thread): idx = r*256+tid
  int bk[4], bn4[4];
#pragma unroll
  for (int r = 0; r < 4; ++r) {
    int idx = r * 256 + tid;
    bk[r] = idx >> 4; bn4[r] = (idx & 15) * 4;
  }
  float4 fa[2][2], fb[4];
  auto loadAB = [&](int k0) {
#pragma unroll
    for (int q = 0; q < 2; ++q) {
      fa[q][0] = *(const float4*)&A[(size_t)arow[q] * 256 + k0 + akb[q]];
      fa[q][1] = *(const float4*)&A[(size_t)arow[q] * 256 + k0 + akb[q] + 16];
    }
#pragma unroll
    for (int r = 0; r < 4; ++r)
      fb[r] = *(const float4*)&W[(size_t)(k0 + bk[r]) * 512 + bn + bn4[r]];
  };
  auto writeAB = [&](int buf) {
#pragma unroll
    for (int q = 0; q < 2; ++q) {
      bf16x8 o;
      o[0] = (short)f2bf(fa[q][0].x); o[1] = (short)f2bf(fa[q][0].y);
      o[2] = (short)f2bf(fa[q][0].z); o[3] = (short)f2bf(fa[q][0].w);
      o[4] = (short)f2bf(fa[q][1].x); o[5] = (short)f2bf(fa[q][1].y);
      o[6] = (short)f2bf(fa[q][1].z); o[7] = (short)f2bf(fa[q][1].w);
      *(bf16x8*)(As[buf] + aslot[q] * 1024 + ale[q] * 16) = o;
    }
#pragma unroll
    for (int r = 0; r < 4; ++r) {
      const int k_l = bk[r], ks = k_l >> 5, w32 = k_l & 31;
      const int hi = (w32 & 15) >> 2, d = w32 & 3, h = (w32 >> 4) & 1;
      const float* fp = reinterpret_cast<const float*>(&fb[r]);
#pragma unroll
      for (int j = 0; j < 4; ++j) {
        const int n = bn4[r] + j;
        *(unsigned short*)(Bs[buf] + ((n >> 4) * 2 + ks) * 1024 +
                           ((hi * 16 + (n & 15)) * 16) + h * 8 + d * 2) = f2bf(fp[j]);
      }
    }
  };

  f32x4 acc[2][2] = {};
  loadAB(0);
#pragma unroll
  for (int st = 0; st < 4; ++st) {
    const int buf = st & 1;
    writeAB(buf);
    __syncthreads();
    if (st < 3) loadAB((st + 1) * 64);
#pragma unroll
    for (int kss = 0; kss < 2; ++kss) {
      bf16x8 af[2], bfv[2];
#pragma unroll
      for (int i = 0; i < 2; ++i)
        af[i] = *(const bf16x8*)(As[buf] + ((wm * 2 + i) * 2 + kss) * 1024 + lane16);
#pragma unroll
      for (int j = 0; j < 2; ++j)
        bfv[j] = *(const bf16x8*)(Bs[buf] + ((wn * 2 + j) * 2 + kss) * 1024 + lane16);
#pragma unroll
      for (int i = 0; i < 2; ++i)
#pragma unroll
        for (int j = 0; j < 2; ++j)
          acc[i][j] = __builtin_amdgcn_mfma_f32_16x16x32_bf16(bfv[j], af[i], acc[i][j], 0, 0, 0);
    }
    __syncthreads();
  }

  // epilogue (N=512): bias + (z==1) action row from gW0 fp32 + relu -> frag-major
  const int l15 = lane & 15, hi = lane >> 4;
  const int row0 = bm + wm * 32;
  const int col0 = bn + wn * 32;
  int ar[2] = {0, 0};
  if (z == 1) {
#pragma unroll
    for (int i = 0; i < 2; ++i) {
      float4 aa = *(const float4*)&a1h[(size_t)(row0 + i * 16 + l15) * 4];
      ar[i] = (aa.y > 0.5f) ? 1 : (aa.z > 0.5f) ? 2 : (aa.w > 0.5f) ? 3 : 0;
    }
  }
  float4 bi0 = *(const float4*)&bias[col0 + hi * 4];
  float4 bi1 = *(const float4*)&bias[col0 + 16 + hi * 4];
#pragma unroll
  for (int i = 0; i < 2; ++i) {
    const int rfC = (row0 >> 4) + i;
    float v[8] = { acc[i][0][0] + bi0.x, acc[i][0][1] + bi0.y,
                   acc[i][0][2] + bi0.z, acc[i][0][3] + bi0.w,
                   acc[i][1][0] + bi1.x, acc[i][1][1] + bi1.y,
                   acc[i][1][2] + bi1.z, acc[i][1][3] + bi1.w };
    if (z == 1) {
      float4 g0 = *(const float4*)&gW0[(size_t)(256 + ar[i]) * 512 + col0 + hi * 4];
      float4 g1 = *(const float4*)&gW0[(size_t)(256 + ar[i]) * 512 + col0 + 16 + hi * 4];
      v[0] += g0.x; v[1] += g0.y; v[2] += g0.z; v[3] += g0.w;
      v[4] += g1.x; v[5] += g1.y; v[6] += g1.z; v[7] += g1.w;
    }
    bf16x8 r;
#pragma unroll
    for (int t = 0; t < 8; ++t) r[t] = (short)f2bf(fmaxf(v[t], 0.f));
    *(bf16x8*)((char*)C + (size_t)(rfC * 16 + (col0 >> 5)) * 1024 + lane16) = r;
  }
}

// ---------------------------------------------------------------- L1 GEMM (R10 gemm_db, FNW=2, K=512)
__global__ __launch_bounds__(256) void gemm_mid(
    const unsigned short* __restrict__ A0, const unsigned short* __restrict__ A1,
    const unsigned short* __restrict__ W0, const unsigned short* __restrict__ W1,
    const float* __restrict__ b0, const float* __restrict__ b1,
    unsigned short* __restrict__ C0, unsigned short* __restrict__ C1) {
  constexpr int K = 512, KS = K >> 5, NSTEP = K >> 6, N = 512;
  __shared__ char lds[2 * 16384];
  char* As = lds;
  char* Bs = lds + 16384;
  const int tid = threadIdx.x, lane = tid & 63, w = tid >> 6;
  const int wm = w >> 1, wn = w & 1;
  const int z = blockIdx.z;
  const char* Ab = (const char*)(z ? A1 : A0);
  const char* Wb = (const char*)(z ? W1 : W0);
  const float* bias = z ? b1 : b0;
  char* Cb = (char*)(z ? C1 : C0);
  const int bm = blockIdx.x * 64, bn = blockIdx.y * 64;
  const int lane16 = lane * 16;

  auto stage = [&](int buf, int st) {
#pragma unroll
    for (int u = 0; u < 2; ++u) {
      const int sl = w * 2 + u;
      const char* srcA = Ab + ((size_t)((bm >> 4) + (sl >> 1)) * KS + st * 2 + (sl & 1)) * 1024 + lane16;
      __builtin_amdgcn_global_load_lds((gas_t)srcA, (las_t)(As + buf * 8192 + sl * 1024), 16, 0, 0);
      const char* srcB = Wb + ((size_t)((bn >> 4) + (sl >> 1)) * KS + st * 2 + (sl & 1)) * 1024 + lane16;
      __builtin_amdgcn_global_load_lds((gas_t)srcB, (las_t)(Bs + buf * 8192 + sl * 1024), 16, 0, 0);
    }
  };

  f32x4 acc[2][2] = {};
  stage(0, 0);
#pragma unroll
  for (int st = 0; st < NSTEP; ++st) {
    const int buf = st & 1;
    if (st + 1 < NSTEP) {
      stage(buf ^ 1, st + 1);
      asm volatile("s_waitcnt vmcnt(4)" ::: "memory");
    } else {
      asm volatile("s_waitcnt vmcnt(0)" ::: "memory");
    }
    __builtin_amdgcn_s_barrier();
#pragma unroll
    for (int kss = 0; kss < 2; ++kss) {
      bf16x8 af[2], bfv[2];
#pragma unroll
      for (int i = 0; i < 2; ++i)
        af[i] = *(const bf16x8*)(As + buf * 8192 + ((wm * 2 + i) * 2 + kss) * 1024 + lane16);
#pragma unroll
      for (int j = 0; j < 2; ++j)
        bfv[j] = *(const bf16x8*)(Bs + buf * 8192 + ((wn * 2 + j) * 2 + kss) * 1024 + lane16);
#pragma unroll
      for (int i = 0; i < 2; ++i)
#pragma unroll
        for (int j = 0; j < 2; ++j)
          acc[i][j] = __builtin_amdgcn_mfma_f32_16x16x32_bf16(bfv[j], af[i], acc[i][j], 0, 0, 0);
    }
    __builtin_amdgcn_s_barrier();
  }

  const int l15 = lane & 15, hi = lane >> 4;
  const int row0 = bm + wm * 32, col0 = bn + wn * 32;
  float4 bi0 = *(const float4*)&bias[col0 + hi * 4];
  float4 bi1 = *(const float4*)&bias[col0 + 16 + hi * 4];
#pragma unroll
  for (int i = 0; i < 2; ++i) {
    const int rfC = (row0 >> 4) + i;
    float v[8] = { acc[i][0][0] + bi0.x, acc[i][0][1] + bi0.y,
                   acc[i][0][2] + bi0.z, acc[i][0][3] + bi0.w,
                   acc[i][1][0] + bi1.x, acc[i][1][1] + bi1.y,
                   acc[i][1][2] + bi1.z, acc[i][1][3] + bi1.w };
    bf16x8 r;
#pragma unroll
    for (int t = 0; t < 8; ++t) r[t] = (short)f2bf(fmaxf(v[t], 0.f));
    *(bf16x8*)(Cb + (size_t)(rfC * (N >> 5) + (col0 >> 5)) * 1024 + lane16) = r;
  }
}

// ---------------------------------------------------------------- L2 GEMM (BM=64, BN=32, K=512) + sqp4 partials + done/out zero
__global__ __launch_bounds__(256) void gemm_l2(
    const unsigned short* __restrict__ A0, const unsigned short* __restrict__ A1,
    const unsigned short* __restrict__ W0, const unsigned short* __restrict__ W1,
    const float* __restrict__ b0, const float* __restrict__ b1,
    unsigned short* __restrict__ C0, unsigned short* __restrict__ C1,
    float* __restrict__ sqp4, unsigned* __restrict__ done, float* __restrict__ out) {
  constexpr int K = 512, KS = K >> 5, NSTEP = K >> 6, N = 128;
  __shared__ char lds[2 * 12288];
  char* As = lds;            // 2 x 8KB
  char* Bs = lds + 16384;    // 2 x 4KB
  __shared__ float sqred[2][64];
  const int tid = threadIdx.x, lane = tid & 63, w = tid >> 6;
  const int wm = w >> 1, wn = w & 1;
  const int z = blockIdx.z;
  if (blockIdx.x == 0 && blockIdx.y == 0 && z == 0) {
    for (int i = tid; i < 1025; i += 256) done[i] = 0;
    if (tid == 0) out[0] = 0.f;
  }
  const char* Ab = (const char*)(z ? A1 : A0);
  const char* Wb = (const char*)(z ? W1 : W0);
  const float* bias = z ? b1 : b0;
  char* Cb = (char*)(z ? C1 : C0);
  const int bm = blockIdx.x * 64, bn = blockIdx.y * 32;
  const int lane16 = lane * 16;

  auto stage = [&](int buf, int st) {
#pragma unroll
    for (int u = 0; u < 2; ++u) {
      const int sl = w * 2 + u;
      const char* srcA = Ab + ((size_t)((bm >> 4) + (sl >> 1)) * KS + st * 2 + (sl & 1)) * 1024 + lane16;
      __builtin_amdgcn_global_load_lds((gas_t)srcA, (las_t)(As + buf * 8192 + sl * 1024), 16, 0, 0);
    }
    const int sl = w;   // 4 B slots (2 nf x 2 ks)
    const char* srcB = Wb + ((size_t)((bn >> 4) + (sl >> 1)) * KS + st * 2 + (sl & 1)) * 1024 + lane16;
    __builtin_amdgcn_global_load_lds((gas_t)srcB, (las_t)(Bs + buf * 4096 + sl * 1024), 16, 0, 0);
  };

  f32x4 acc[2] = {};
  stage(0, 0);
#pragma unroll
  for (int st = 0; st < NSTEP; ++st) {
    const int buf = st & 1;
    if (st + 1 < NSTEP) {
      stage(buf ^ 1, st + 1);
      asm volatile("s_waitcnt vmcnt(3)" ::: "memory");
    } else {
      asm volatile("s_waitcnt vmcnt(0)" ::: "memory");
    }
    __builtin_amdgcn_s_barrier();
#pragma unroll
    for (int kss = 0; kss < 2; ++kss) {
      bf16x8 af[2], bfv;
#pragma unroll
      for (int i = 0; i < 2; ++i)
        af[i] = *(const bf16x8*)(As + buf * 8192 + ((wm * 2 + i) * 2 + kss) * 1024 + lane16);
      bfv = *(const bf16x8*)(Bs + buf * 4096 + (wn * 2 + kss) * 1024 + lane16);
#pragma unroll
      for (int i = 0; i < 2; ++i)
        acc[i] = __builtin_amdgcn_mfma_f32_16x16x32_bf16(bfv, af[i], acc[i], 0, 0, 0);
    }
    __builtin_amdgcn_s_barrier();
  }

  const int l15 = lane & 15, hi = lane >> 4;
  const int row0 = bm + wm * 32;
  const int col0 = bn + wn * 16;
  float4 bi0 = *(const float4*)&bias[col0 + hi * 4];
  float sq[2] = {0.f, 0.f};
#pragma unroll
  for (int i = 0; i < 2; ++i) {
    const int rfC = (row0 >> 4) + i;
    float v[4] = { acc[i][0] + bi0.x, acc[i][1] + bi0.y, acc[i][2] + bi0.z, acc[i][3] + bi0.w };
    short4v r;
#pragma unroll
    for (int t = 0; t < 4; ++t) {
      unsigned short cv = f2bf(v[t]);
      r[t] = (short)cv;
      float vb = bf2f(cv);
      sq[i] += vb * vb;
    }
    *(short4v*)(Cb + (size_t)(rfC * (N >> 5) + (bn >> 5)) * 1024 + lane16 + wn * 8) = r;
  }
#pragma unroll
  for (int i = 0; i < 2; ++i) {
    float t = sq[i];
    t += __shfl_xor(t, 16, 64);
    t += __shfl_xor(t, 32, 64);
    if (lane < 16) sqred[wn][wm * 32 + i * 16 + lane] = t;
  }
  __syncthreads();
  if (z == 1 && tid < 64)
    sqp4[(size_t)blockIdx.y * NR + bm + tid] = sqred[0][tid] + sqred[1][tid];
}

// ---------------------------------------------------------------- logits + tail finalize
// grid (32, 32): block = 128 rows x 128 j; Zp panel LDS-staged; last-16 blocks finalize.
__global__ __launch_bounds__(256) void logits_fin(
    const unsigned short* __restrict__ Zb, const unsigned short* __restrict__ Zpb,
    const float* __restrict__ sqp4, float* __restrict__ wm_,
    float* __restrict__ wsum, float* __restrict__ wdiag,
    unsigned* __restrict__ done, float* __restrict__ out) {
  __shared__ __align__(1024) char Ps[32768];
  __shared__ int hid;
  __shared__ float fpart[4];
  const int tid = threadIdx.x, lane = tid & 63, w = tid >> 6;
  const int l15 = lane & 15, hi = lane >> 4;
  const int bx = blockIdx.x, jr = blockIdx.y;
  const int i0 = bx * 128;
  const int row32 = i0 + w * 32;
  const int jbase = jr * 128;
  const int lane16 = lane * 16;
  const char* Zc = (const char*)Zb;
  const char* Pc = (const char*)Zpb;

  // stage the 32KB contiguous Zp j-panel into LDS (shared by 4 waves)
#pragma unroll
  for (int u = 0; u < 8; ++u) {
    const int sl = w * 8 + u;
    __builtin_amdgcn_global_load_lds(
        (gas_t)(Pc + ((size_t)(jbase >> 4) * 4 + sl) * 1024 + lane16),
        (las_t)(Ps + sl * 1024), 16, 0, 0);
  }
  bf16x8 afr[2][4];
#pragma unroll
  for (int rf = 0; rf < 2; ++rf)
#pragma unroll
    for (int ks = 0; ks < 4; ++ks)
      afr[rf][ks] = *(const bf16x8*)(Zc + (size_t)(((row32 >> 4) + rf) * 4 + ks) * 1024 + lane16);
  asm volatile("s_waitcnt vmcnt(0)" ::: "memory");
  __syncthreads();

  f32x4 acc[2][8] = {};
#pragma unroll
  for (int ks = 0; ks < 4; ++ks)
#pragma unroll
    for (int jf = 0; jf < 8; ++jf) {
      bf16x8 bfv = *(const bf16x8*)(Ps + (jf * 4 + ks) * 1024 + lane16);
      acc[0][jf] = __builtin_amdgcn_mfma_f32_16x16x32_bf16(bfv, afr[0][ks], acc[0][jf], 0, 0, 0);
      acc[1][jf] = __builtin_amdgcn_mfma_f32_16x16x32_bf16(bfv, afr[1][ks], acc[1][jf], 0, 0, 0);
    }

#pragma unroll
  for (int rf = 0; rf < 2; ++rf) {
    const int grow = row32 + rf * 16 + l15;
    float mx = -INFINITY, dd = 0.f;
    bool hasd = false;
#pragma unroll
    for (int jf = 0; jf < 8; ++jf) {
      const int cb = jbase + jf * 16 + hi * 4;
      float4 q0 = *(const float4*)&sqp4[cb];
      float4 q1 = *(const float4*)&sqp4[NR + cb];
      float4 q2 = *(const float4*)&sqp4[2 * NR + cb];
      float4 q3 = *(const float4*)&sqp4[3 * NR + cb];
      float sp[4] = { q0.x + q1.x + q2.x + q3.x, q0.y + q1.y + q2.y + q3.y,
                      q0.z + q1.z + q2.z + q3.z, q0.w + q1.w + q2.w + q3.w };
#pragma unroll
      for (int e = 0; e < 4; ++e) {
        float lv = (2.f * acc[rf][jf][e] - sp[e]) * INV_T;
        acc[rf][jf][e] = lv;
        mx = fmaxf(mx, lv);
        if (cb + e == grow) { dd = lv; hasd = true; }
      }
    }
    mx = fmaxf(mx, __shfl_xor(mx, 16, 64));
    mx = fmaxf(mx, __shfl_xor(mx, 32, 64));
    float sum = 0.f;
#pragma unroll
    for (int jf = 0; jf < 8; ++jf)
#pragma unroll
      for (int e = 0; e < 4; ++e) sum += __expf(acc[rf][jf][e] - mx);
    sum += __shfl_xor(sum, 16, 64);
    sum += __shfl_xor(sum, 32, 64);
    if (hi == 0) {
      wm_[(size_t)jr * NR + grow] = mx;
      wsum[(size_t)jr * NR + grow] = sum;
    }
    if (hasd) wdiag[grow] = dd;
  }

  // ---- arrival protocol: 64 spread lines (16 blocks each), then final counter ----
  __syncthreads();   // drains this block's global stores (vmcnt0 before barrier)
  if (tid == 0) {
    hid = -1;
    const int bid = jr * 32 + bx;
    unsigned old = __hip_atomic_fetch_add(&done[(bid & 63) * 16], 1u,
                                          __ATOMIC_RELEASE, __HIP_MEMORY_SCOPE_AGENT);
    if (old == 15u) {
      unsigned f = __hip_atomic_fetch_add(&done[DONE_FINAL], 1u,
                                          __ATOMIC_RELEASE, __HIP_MEMORY_SCOPE_AGENT);
      if (f >= 48u) {
        while (__hip_atomic_load(&done[DONE_FINAL], __ATOMIC_ACQUIRE,
                                 __HIP_MEMORY_SCOPE_AGENT) < 64u)
          __builtin_amdgcn_s_sleep(16);
        hid = (int)(f - 48u);
      }
    }
  }
  __syncthreads();
  if (hid < 0) return;

  // ---- tail finalize: this block handles rows [hid*256, hid*256+256) ----
  {
    const int r = hid * 256 + tid;
    float mm = wm_[r];
    float ss = wsum[r];
#pragma unroll
    for (int p = 1; p < NJR; ++p) {
      float mo = wm_[(size_t)p * NR + r];
      float so = wsum[(size_t)p * NR + r];
      float mn = fmaxf(mm, mo);
      ss = ss * __expf(mm - mn) + so * __expf(mo - mn);
      mm = mn;
    }
    float v = mm + logf(ss) - wdiag[r];
#pragma unroll
    for (int off = 32; off; off >>= 1) v += __shfl_xor(v, off, 64);
    if (lane == 0) fpart[w] = v;
    __syncthreads();
    if (tid == 0)
      atomicAdd(out, (fpart[0] + fpart[1] + fpart[2] + fpart[3]) * (1.0f / (float)NR));
  }
}

// ---------------------------------------------------------------- launch (4 dispatches)
extern "C" void kernel_launch(void* const* d_in, const int* in_sizes, int n_in,
                              void* d_out, int out_size, void* d_ws, size_t ws_size,
                              hipStream_t stream) {
  const float* s   = (const float*)d_in[0];
  const float* sp  = (const float*)d_in[1];
  const float* a1h = (const float*)d_in[2];
  const float* pW0 = (const float*)d_in[3];
  const float* pb0 = (const float*)d_in[4];
  const float* pW1 = (const float*)d_in[5];
  const float* pb1 = (const float*)d_in[6];
  const float* pW2 = (const float*)d_in[7];
  const float* pb2 = (const float*)d_in[8];
  const float* gW0 = (const float*)d_in[9];
  const float* gb0 = (const float*)d_in[10];
  const float* gW1 = (const float*)d_in[11];
  const float* gb1 = (const float*)d_in[12];
  const float* gW2 = (const float*)d_in[13];
  const float* gb2 = (const float*)d_in[14];

  char* p = (char*)d_ws;
  unsigned short* H1   = (unsigned short*)p; p += (size_t)2 * NR * HD * 2;
  unsigned short* H2   = (unsigned short*)p; p += (size_t)2 * NR * HD * 2;
  unsigned short* Zall = (unsigned short*)p; p += (size_t)2 * NR * 128 * 2;
  unsigned short* pW1t = (unsigned short*)p; p += (size_t)512 * 512 * 2;
  unsigned short* pW2t = (unsigned short*)p; p += (size_t)512 * 128 * 2;
  unsigned short* gW1t = (unsigned short*)p; p += (size_t)512 * 512 * 2;
  unsigned short* gW2t = (unsigned short*)p; p += (size_t)512 * 128 * 2;
  float* sqp4 = (float*)p; p += (size_t)4 * NR * 4;
  float* wm   = (float*)p; p += (size_t)NJR * NR * 4;
  float* wsm  = (float*)p; p += (size_t)NJR * NR * 4;
  float* wdg  = (float*)p; p += (size_t)NR * 4;
  unsigned* done = (unsigned*)p; p += 8192;

  unsigned short* H1g = H1 + (size_t)NR * HD;
  unsigned short* H2g = H2 + (size_t)NR * HD;
  unsigned short* Zb  = Zall;
  unsigned short* Zpb = Zall + (size_t)NR * 128;

  dim3 blk(256);
  l0_fused<<<1664, blk, 0, stream>>>(s, sp, a1h, pW0, gW0, pb0, gb0, H1, H1g,
                                     pW1, pW1t, pW2, pW2t, gW1, gW1t, gW2, gW2t);
  gemm_mid<<<dim3(64, 8, 2), blk, 0, stream>>>(H1, H1g, pW1t, gW1t, pb1, gb1, H2, H2g);
  gemm_l2<<<dim3(64, 4, 2), blk, 0, stream>>>(H2, H2g, pW2t, gW2t, pb2, gb2, Zb, Zpb,
                                              sqp4, done, (float*)d_out);
  logits_fin<<<dim3(32, 32), blk, 0, stream>>>(Zb, Zpb, sqp4, wm, wsm, wdg,
                                               done, (float*)d_out);
}